// Round 7
// baseline (1855.193 us; speedup 1.0000x reference)
//
#include <hip/hip_runtime.h>

#define NT 1024
#define H0S 256   // h0 ring slots (4 KB each)
#define GXS 64    // gx0 ring slots (32 KB each)
#define GYS 64    // gy1 ring slots (32 KB each)

typedef _Float16 half8 __attribute__((ext_vector_type(8)));
typedef _Float16 half4 __attribute__((ext_vector_type(4)));
typedef float f32x4 __attribute__((ext_vector_type(4)));
typedef unsigned long long u64;
struct U2 { u64 a, b; };

__device__ __forceinline__ f32x4 MFMA(half8 a, half8 b, f32x4 c) {
  return __builtin_amdgcn_mfma_f32_16x16x32_f16(a, b, c, 0, 0, 0);
}
__device__ __forceinline__ float sigf(float x) {
  return __builtin_amdgcn_rcpf(1.0f + __expf(-x));
}
__device__ __forceinline__ float tanhf2(float x) {
  float ax = fabsf(x);
  float e = __expf(-2.0f * ax);
  float t = (1.0f - e) * __builtin_amdgcn_rcpf(1.0f + e);
  return copysignf(t, x);
}
__device__ __forceinline__ half8 cvt8(float4 c0, float4 c1) {
  half8 hv;
  hv[0] = (_Float16)c0.x; hv[1] = (_Float16)c0.y;
  hv[2] = (_Float16)c0.z; hv[3] = (_Float16)c0.w;
  hv[4] = (_Float16)c1.x; hv[5] = (_Float16)c1.y;
  hv[6] = (_Float16)c1.z; hv[7] = (_Float16)c1.w;
  return hv;
}
__device__ __forceinline__ half8 ldringh(const _Float16* p) {
  const u64* q = (const u64*)p;
  U2 uu;
  uu.a = __hip_atomic_load(q, __ATOMIC_RELAXED, __HIP_MEMORY_SCOPE_AGENT);
  uu.b = __hip_atomic_load(q + 1, __ATOMIC_RELAXED, __HIP_MEMORY_SCOPE_AGENT);
  return __builtin_bit_cast(half8, uu);
}
__device__ __forceinline__ f32x4 ld16f(const float* p) {
  const u64* q = (const u64*)p;
  U2 uu;
  uu.a = __hip_atomic_load(q, __ATOMIC_RELAXED, __HIP_MEMORY_SCOPE_AGENT);
  uu.b = __hip_atomic_load(q + 1, __ATOMIC_RELAXED, __HIP_MEMORY_SCOPE_AGENT);
  return __builtin_bit_cast(f32x4, uu);
}
__device__ __forceinline__ void st16f(float* p, f32x4 v) {
  U2 uu = __builtin_bit_cast(U2, v);
  __hip_atomic_store((u64*)p, uu.a, __ATOMIC_RELAXED, __HIP_MEMORY_SCOPE_AGENT);
  __hip_atomic_store((u64*)p + 1, uu.b, __ATOMIC_RELAXED, __HIP_MEMORY_SCOPE_AGENT);
}
__device__ __forceinline__ void st8h(_Float16* p, half4 v) {
  u64 uh = __builtin_bit_cast(u64, v);
  __hip_atomic_store((u64*)p, uh, __ATOMIC_RELAXED, __HIP_MEMORY_SCOPE_AGENT);
}
__device__ __forceinline__ unsigned wpoll(unsigned* p, unsigned tgt,
                                          unsigned cached, int l) {
  unsigned c = cached;
  while (c < tgt) {
    unsigned pv = 0;
    if (l == 0)
      pv = __hip_atomic_load(p, __ATOMIC_ACQUIRE, __HIP_MEMORY_SCOPE_AGENT);
    c = (unsigned)__builtin_amdgcn_readfirstlane((int)pv);
    if (c < tgt) __builtin_amdgcn_s_sleep(2);
  }
  return c;
}

// 32 blocks x 512 threads; role = bid>>3 (0=X0 gx GEMM, 1=P layer-0 recur,
// 2=X1 gy GEMM, 3=Y layer-1 recur + FC), g = bid&7 (16 batch rows each).
// Recurrent blocks P/Y carry ONLY the Whh MFMAs (16/wave) + cell; the Wih
// halves are streamed by X0/X1 through f32 rings in the C-fragment layout
// so acc-init is a plain prefetched 16B load. All cross-CU handoff uses
// agent-scope relaxed data + amortized drained-release flags (R6 pattern).
__global__ __launch_bounds__(512, 1) void lstm_main(
    const float* __restrict__ x,
    const float* __restrict__ wih0, const float* __restrict__ whh0,
    const float* __restrict__ wih1, const float* __restrict__ whh1,
    const float* __restrict__ bih, const float* __restrict__ bhh,
    const float* __restrict__ fcw, const float* __restrict__ fcb,
    _Float16* __restrict__ ringH0, float* __restrict__ ringGX,
    float* __restrict__ ringGY, unsigned* __restrict__ flags,
    float* __restrict__ out) {
  const int tid = threadIdx.x;
  const int w = tid >> 6, l = tid & 63;
  const int n = l & 15, lg = l >> 4;
  const int role = blockIdx.x >> 3;
  const int g = blockIdx.x & 7;

  __shared__ _Float16 hfr[2][4][64][8];   // recurrent h frag ring (8 KB)
  __shared__ _Float16 fcl[4][4][64][8];   // FC A-frags (Y only, 16 KB)

  _Float16* h0G = ringH0 + (size_t)g * H0S * 2048;
  float* gxG = ringGX + (size_t)g * GXS * 8192;
  float* gyG = ringGY + (size_t)g * GYS * 8192;
  unsigned* pX0 = flags + (0 * 8 + g) * 16;
  unsigned* pP  = flags + (1 * 8 + g) * 16;
  unsigned* pX1 = flags + (2 * 8 + g) * 16;
  unsigned* cY  = flags + (3 * 8 + g) * 16;
  const half8 hz = {0, 0, 0, 0, 0, 0, 0, 0};

  if (role == 0) {
    // ================= X0: gx0[s] = Wih0 x[s] + b0 (no deps) =================
    half8 A[4][2];
    f32x4 bias[4];
#pragma unroll
    for (int q = 0; q < 4; ++q) {
      int row = (w + 8 * q) * 16 + n;
#pragma unroll
      for (int kt = 0; kt < 2; ++kt) {
        const float* wp = wih0 + (size_t)row * 64 + kt * 32 + lg * 4;
        A[q][kt] = cvt8(*(const float4*)wp, *(const float4*)(wp + 16));
      }
      int rb = (w + 8 * q) * 16 + lg * 4;
      f32x4 bv;
#pragma unroll
      for (int r = 0; r < 4; ++r) bv[r] = bih[rb + r] + bhh[rb + r];
      bias[q] = bv;
    }
    const float* xL = x + (size_t)(g * 16 + n) * NT * 64 + lg * 4;
    float4 c00 = *(const float4*)(xL);
    float4 c01 = *(const float4*)(xL + 16);
    float4 c10 = *(const float4*)(xL + 32);
    float4 c11 = *(const float4*)(xL + 48);
    unsigned Pp = 0;
    for (int u = 0; u < NT; ++u) {
      float4 n00, n01, n10, n11;
      if (u + 1 < NT) {
        const float* p = xL + (size_t)(u + 1) * 64;
        n00 = *(const float4*)(p);
        n01 = *(const float4*)(p + 16);
        n10 = *(const float4*)(p + 32);
        n11 = *(const float4*)(p + 48);
      }
      half8 b0 = cvt8(c00, c01), b1 = cvt8(c10, c11);
      f32x4 a0 = bias[0], a1 = bias[1], a2 = bias[2], a3 = bias[3];
      a0 = MFMA(A[0][0], b0, a0); a1 = MFMA(A[1][0], b0, a1);
      a2 = MFMA(A[2][0], b0, a2); a3 = MFMA(A[3][0], b0, a3);
      a0 = MFMA(A[0][1], b1, a0); a1 = MFMA(A[1][1], b1, a1);
      a2 = MFMA(A[2][1], b1, a2); a3 = MFMA(A[3][1], b1, a3);
      float* gp = gxG + (size_t)(u & (GXS - 1)) * 8192;
      st16f(gp + ((w + 0) * 64 + l) * 4, a0);
      st16f(gp + ((w + 8) * 64 + l) * 4, a1);
      st16f(gp + ((w + 16) * 64 + l) * 4, a2);
      st16f(gp + ((w + 24) * 64 + l) * 4, a3);
      if (u >= 64 && (u & 15) == 0)  // ring backpressure vs P (cap 48)
        Pp = wpoll(pP, (unsigned)(u - 48), Pp, l);
      if ((u & 7) == 7) {  // drained release publish
        asm volatile("s_waitcnt vmcnt(0)" ::: "memory");
        __builtin_amdgcn_sched_barrier(0);
        __builtin_amdgcn_s_barrier();
        __builtin_amdgcn_sched_barrier(0);
        if (tid == 0)
          __hip_atomic_store(pX0, (unsigned)(u + 1), __ATOMIC_RELEASE,
                             __HIP_MEMORY_SCOPE_AGENT);
      }
      c00 = n00; c01 = n01; c10 = n10; c11 = n11;
    }
  } else if (role == 1) {
    // ============ P: layer-0 recurrence (Whh0 only, 16 MFMA/wave) ============
    half8 A[4][4];
#pragma unroll
    for (int q = 0; q < 4; ++q) {
      int row = (w + 8 * q) * 16 + n;
#pragma unroll
      for (int kt = 0; kt < 4; ++kt) {
        const float* wp = whh0 + (size_t)row * 128 + kt * 32 + lg * 4;
        A[q][kt] = cvt8(*(const float4*)wp, *(const float4*)(wp + 16));
      }
    }
    if (tid < 256) ((half8*)&hfr[1][0][0][0])[tid] = hz;  // h0[-1]=0
    f32x4 cst = {0.f, 0.f, 0.f, 0.f};
    unsigned Px = 0, X1p = 0;
    __syncthreads();
    Px = wpoll(pX0, 2u, 0u, l);
    f32x4 gA0 = ld16f(gxG + ((w + 0) * 64 + l) * 4);
    f32x4 gA1 = ld16f(gxG + ((w + 8) * 64 + l) * 4);
    f32x4 gA2 = ld16f(gxG + ((w + 16) * 64 + l) * 4);
    f32x4 gA3 = ld16f(gxG + ((w + 24) * 64 + l) * 4);
    const float* g1p = gxG + 8192;
    f32x4 gB0 = ld16f(g1p + ((w + 0) * 64 + l) * 4);
    f32x4 gB1 = ld16f(g1p + ((w + 8) * 64 + l) * 4);
    f32x4 gB2 = ld16f(g1p + ((w + 16) * 64 + l) * 4);
    f32x4 gB3 = ld16f(g1p + ((w + 24) * 64 + l) * 4);

#define PSTEP(T, G0, G1, G2, G3)                                               \
  {                                                                            \
    const int rdk_ = ((T) + 1) & 1;                                            \
    half8 b0_ = *(const half8*)&hfr[rdk_][0][l][0];                            \
    half8 b1_ = *(const half8*)&hfr[rdk_][1][l][0];                            \
    half8 b2_ = *(const half8*)&hfr[rdk_][2][l][0];                            \
    half8 b3_ = *(const half8*)&hfr[rdk_][3][l][0];                            \
    f32x4 a0 = G0, a1 = G1, a2 = G2, a3 = G3;                                  \
    a0 = MFMA(A[0][0], b0_, a0); a1 = MFMA(A[1][0], b0_, a1);                  \
    a2 = MFMA(A[2][0], b0_, a2); a3 = MFMA(A[3][0], b0_, a3);                  \
    a0 = MFMA(A[0][1], b1_, a0); a1 = MFMA(A[1][1], b1_, a1);                  \
    a2 = MFMA(A[2][1], b1_, a2); a3 = MFMA(A[3][1], b1_, a3);                  \
    a0 = MFMA(A[0][2], b2_, a0); a1 = MFMA(A[1][2], b2_, a1);                  \
    a2 = MFMA(A[2][2], b2_, a2); a3 = MFMA(A[3][2], b2_, a3);                  \
    a0 = MFMA(A[0][3], b3_, a0); a1 = MFMA(A[1][3], b3_, a1);                  \
    a2 = MFMA(A[2][3], b3_, a2); a3 = MFMA(A[3][3], b3_, a3);                  \
    if ((T) + 2 < NT) { /* prefetch gx0[T+2]; stays in flight over barrier */  \
      Px = wpoll(pX0, (unsigned)((T) + 3), Px, l);                             \
      const float* gp_ = gxG + (size_t)(((T) + 2) & (GXS - 1)) * 8192;         \
      G0 = ld16f(gp_ + ((w + 0) * 64 + l) * 4);                                \
      G1 = ld16f(gp_ + ((w + 8) * 64 + l) * 4);                                \
      G2 = ld16f(gp_ + ((w + 16) * 64 + l) * 4);                               \
      G3 = ld16f(gp_ + ((w + 24) * 64 + l) * 4);                               \
    }                                                                          \
    half4 hh;                                                                  \
    _Pragma("unroll")                                                          \
    for (int r = 0; r < 4; ++r) {                                              \
      float iv = sigf(a0[r]), fv = sigf(a1[r]);                                \
      float gv = tanhf2(a2[r]), ov = sigf(a3[r]);                              \
      cst[r] = fv * cst[r] + iv * gv;                                          \
      hh[r] = (_Float16)(ov * tanhf2(cst[r]));                                 \
    }                                                                          \
    *(half4*)&hfr[(T) & 1][w >> 1][l][(w & 1) << 2] = hh;                      \
    st8h(h0G + (size_t)((T) & (H0S - 1)) * 2048 + (w >> 1) * 512 + l * 8 +     \
             (w & 1) * 4, hh);                                                 \
    if ((T) >= 224 && ((T) & 31) == 0) /* h0 ring cap 192 vs X1 progress */    \
      X1p = wpoll(pX1, (unsigned)((T) - 192), X1p, l);                         \
    asm volatile("s_waitcnt lgkmcnt(0)" ::: "memory");                         \
    __builtin_amdgcn_sched_barrier(0);                                         \
    __builtin_amdgcn_s_barrier(); /* ring stores stay in flight */             \
    __builtin_amdgcn_sched_barrier(0);                                         \
    if (((T) & 31) == 31) { /* amortized drained publish */                    \
      asm volatile("s_waitcnt vmcnt(0)" ::: "memory");                         \
      __builtin_amdgcn_sched_barrier(0);                                       \
      __builtin_amdgcn_s_barrier();                                            \
      __builtin_amdgcn_sched_barrier(0);                                       \
      if (tid == 0)                                                            \
        __hip_atomic_store(pP, (unsigned)((T) + 1), __ATOMIC_RELEASE,          \
                           __HIP_MEMORY_SCOPE_AGENT);                          \
    }                                                                          \
  }

    for (int s = 0; s < NT; s += 2) {
      PSTEP(s, gA0, gA1, gA2, gA3);
      PSTEP(s + 1, gB0, gB1, gB2, gB3);
    }
#undef PSTEP
  } else if (role == 2) {
    // ============ X1: gy1[u] = Wih1 h0[u] + b1 (streaming GEMM) ============
    half8 A[4][4];
    f32x4 bias[4];
#pragma unroll
    for (int q = 0; q < 4; ++q) {
      int row = (w + 8 * q) * 16 + n;
#pragma unroll
      for (int kt = 0; kt < 4; ++kt) {
        const float* wp = wih1 + (size_t)row * 128 + kt * 32 + lg * 4;
        A[q][kt] = cvt8(*(const float4*)wp, *(const float4*)(wp + 16));
      }
      int rb = (w + 8 * q) * 16 + lg * 4;
      f32x4 bv;
#pragma unroll
      for (int r = 0; r < 4; ++r)
        bv[r] = bih[512 + rb + r] + bhh[512 + rb + r];
      bias[q] = bv;
    }
    unsigned Pp = wpoll(pP, 2u, 0u, l), cYp = 0;
    half8 hA0 = ldringh(h0G + l * 8);
    half8 hA1 = ldringh(h0G + 512 + l * 8);
    half8 hA2 = ldringh(h0G + 1024 + l * 8);
    half8 hA3 = ldringh(h0G + 1536 + l * 8);
    const _Float16* h1p = h0G + 2048 + l * 8;
    half8 hB0 = ldringh(h1p);
    half8 hB1 = ldringh(h1p + 512);
    half8 hB2 = ldringh(h1p + 1024);
    half8 hB3 = ldringh(h1p + 1536);

#define XSTEP(U, H0_, H1_, H2_, H3_)                                           \
  {                                                                            \
    f32x4 a0 = bias[0], a1 = bias[1], a2 = bias[2], a3 = bias[3];              \
    a0 = MFMA(A[0][0], H0_, a0); a1 = MFMA(A[1][0], H0_, a1);                  \
    a2 = MFMA(A[2][0], H0_, a2); a3 = MFMA(A[3][0], H0_, a3);                  \
    a0 = MFMA(A[0][1], H1_, a0); a1 = MFMA(A[1][1], H1_, a1);                  \
    a2 = MFMA(A[2][1], H1_, a2); a3 = MFMA(A[3][1], H1_, a3);                  \
    a0 = MFMA(A[0][2], H2_, a0); a1 = MFMA(A[1][2], H2_, a1);                  \
    a2 = MFMA(A[2][2], H2_, a2); a3 = MFMA(A[3][2], H2_, a3);                  \
    a0 = MFMA(A[0][3], H3_, a0); a1 = MFMA(A[1][3], H3_, a1);                  \
    a2 = MFMA(A[2][3], H3_, a2); a3 = MFMA(A[3][3], H3_, a3);                  \
    if ((U) + 2 < NT) { /* prefetch h0[U+2] */                                 \
      Pp = wpoll(pP, (unsigned)((U) + 3), Pp, l);                              \
      const _Float16* hp_ =                                                    \
          h0G + (size_t)(((U) + 2) & (H0S - 1)) * 2048 + l * 8;                \
      H0_ = ldringh(hp_);        H1_ = ldringh(hp_ + 512);                     \
      H2_ = ldringh(hp_ + 1024); H3_ = ldringh(hp_ + 1536);                    \
    }                                                                          \
    float* gp_ = gyG + (size_t)((U) & (GYS - 1)) * 8192;                       \
    st16f(gp_ + ((w + 0) * 64 + l) * 4, a0);                                   \
    st16f(gp_ + ((w + 8) * 64 + l) * 4, a1);                                   \
    st16f(gp_ + ((w + 16) * 64 + l) * 4, a2);                                  \
    st16f(gp_ + ((w + 24) * 64 + l) * 4, a3);                                  \
    if ((U) >= 40 && ((U) & 7) == 0) /* gy ring cap 40 vs Y consumption */     \
      cYp = wpoll(cY, (unsigned)((U) - 40), cYp, l);                           \
    if (((U) & 7) == 7) { /* drained release publish */                        \
      asm volatile("s_waitcnt vmcnt(0)" ::: "memory");                         \
      __builtin_amdgcn_sched_barrier(0);                                       \
      __builtin_amdgcn_s_barrier();                                            \
      __builtin_amdgcn_sched_barrier(0);                                       \
      if (tid == 0)                                                            \
        __hip_atomic_store(pX1, (unsigned)((U) + 1), __ATOMIC_RELEASE,         \
                           __HIP_MEMORY_SCOPE_AGENT);                          \
    }                                                                          \
  }

    for (int u = 0; u < NT; u += 2) {
      XSTEP(u, hA0, hA1, hA2, hA3);
      XSTEP(u + 1, hB0, hB1, hB2, hB3);
    }
#undef XSTEP
  } else {
    // ========= Y: layer-1 recurrence (Whh1, 16 MFMA/wave) + FC + out =========
    half8 A[4][4];
    f32x4 fcbv = {0.f, 0.f, 0.f, 0.f};
#pragma unroll
    for (int q = 0; q < 4; ++q) {
      int row = (w + 8 * q) * 16 + n;
#pragma unroll
      for (int kt = 0; kt < 4; ++kt) {
        const float* wp = whh1 + (size_t)row * 128 + kt * 32 + lg * 4;
        A[q][kt] = cvt8(*(const float4*)wp, *(const float4*)(wp + 16));
      }
    }
    if (w < 4) {  // FC A-frags -> LDS
      int frow = (w << 4) + n;
#pragma unroll
      for (int kt = 0; kt < 4; ++kt) {
        const float* wp = fcw + (size_t)frow * 128 + kt * 32 + lg * 4;
        *(half8*)&fcl[w][kt][l][0] =
            cvt8(*(const float4*)wp, *(const float4*)(wp + 16));
      }
      fcbv = *(const f32x4*)(fcb + (w << 4) + lg * 4);
    }
    if (tid < 256) ((half8*)&hfr[1][0][0][0])[tid] = hz;  // h1[-1]=0
    float* outG = out + (size_t)((g << 4) + n) * NT * 64 + (w << 4) + lg * 4;
    f32x4 cst = {0.f, 0.f, 0.f, 0.f};
    unsigned X1p = 0;
    __syncthreads();
    X1p = wpoll(pX1, 2u, 0u, l);
    f32x4 gA0 = ld16f(gyG + ((w + 0) * 64 + l) * 4);
    f32x4 gA1 = ld16f(gyG + ((w + 8) * 64 + l) * 4);
    f32x4 gA2 = ld16f(gyG + ((w + 16) * 64 + l) * 4);
    f32x4 gA3 = ld16f(gyG + ((w + 24) * 64 + l) * 4);
    const float* g1p = gyG + 8192;
    f32x4 gB0 = ld16f(g1p + ((w + 0) * 64 + l) * 4);
    f32x4 gB1 = ld16f(g1p + ((w + 8) * 64 + l) * 4);
    f32x4 gB2 = ld16f(g1p + ((w + 16) * 64 + l) * 4);
    f32x4 gB3 = ld16f(g1p + ((w + 24) * 64 + l) * 4);

#define YSTEP(T, G0, G1, G2, G3)                                               \
  {                                                                            \
    const int rdk_ = ((T) + 1) & 1;                                            \
    half8 b0_ = *(const half8*)&hfr[rdk_][0][l][0];                            \
    half8 b1_ = *(const half8*)&hfr[rdk_][1][l][0];                            \
    half8 b2_ = *(const half8*)&hfr[rdk_][2][l][0];                            \
    half8 b3_ = *(const half8*)&hfr[rdk_][3][l][0];                            \
    f32x4 a0 = G0, a1 = G1, a2 = G2, a3 = G3;                                  \
    a0 = MFMA(A[0][0], b0_, a0); a1 = MFMA(A[1][0], b0_, a1);                  \
    a2 = MFMA(A[2][0], b0_, a2); a3 = MFMA(A[3][0], b0_, a3);                  \
    a0 = MFMA(A[0][1], b1_, a0); a1 = MFMA(A[1][1], b1_, a1);                  \
    a2 = MFMA(A[2][1], b1_, a2); a3 = MFMA(A[3][1], b1_, a3);                  \
    a0 = MFMA(A[0][2], b2_, a0); a1 = MFMA(A[1][2], b2_, a1);                  \
    a2 = MFMA(A[2][2], b2_, a2); a3 = MFMA(A[3][2], b2_, a3);                  \
    a0 = MFMA(A[0][3], b3_, a0); a1 = MFMA(A[1][3], b3_, a1);                  \
    a2 = MFMA(A[2][3], b3_, a2); a3 = MFMA(A[3][3], b3_, a3);                  \
    if ((T) + 2 < NT) { /* prefetch gy1[T+2] */                                \
      X1p = wpoll(pX1, (unsigned)((T) + 3), X1p, l);                           \
      const float* gp_ = gyG + (size_t)(((T) + 2) & (GYS - 1)) * 8192;         \
      G0 = ld16f(gp_ + ((w + 0) * 64 + l) * 4);                                \
      G1 = ld16f(gp_ + ((w + 8) * 64 + l) * 4);                                \
      G2 = ld16f(gp_ + ((w + 16) * 64 + l) * 4);                               \
      G3 = ld16f(gp_ + ((w + 24) * 64 + l) * 4);                               \
    }                                                                          \
    if (w < 4) { /* FC of h1[T-1] */                                           \
      half8 f0 = *(const half8*)&fcl[w][0][l][0];                              \
      half8 f1 = *(const half8*)&fcl[w][1][l][0];                              \
      half8 f2 = *(const half8*)&fcl[w][2][l][0];                              \
      half8 f3 = *(const half8*)&fcl[w][3][l][0];                              \
      f32x4 afc = fcbv;                                                        \
      afc = MFMA(f0, b0_, afc); afc = MFMA(f1, b1_, afc);                      \
      afc = MFMA(f2, b2_, afc); afc = MFMA(f3, b3_, afc);                      \
      if ((T) >= 1) *(f32x4*)(outG + (size_t)((T) - 1) * 64) = afc;            \
    }                                                                          \
    half4 hh;                                                                  \
    _Pragma("unroll")                                                          \
    for (int r = 0; r < 4; ++r) {                                              \
      float iv = sigf(a0[r]), fv = sigf(a1[r]);                                \
      float gv = tanhf2(a2[r]), ov = sigf(a3[r]);                              \
      cst[r] = fv * cst[r] + iv * gv;                                          \
      hh[r] = (_Float16)(ov * tanhf2(cst[r]));                                 \
    }                                                                          \
    *(half4*)&hfr[(T) & 1][w >> 1][l][(w & 1) << 2] = hh;                      \
    if (tid == 0 && ((T) & 15) == 0) /* consumption pointer: no drain needed */\
      __hip_atomic_store(cY, (unsigned)(T), __ATOMIC_RELAXED,                  \
                         __HIP_MEMORY_SCOPE_AGENT);                            \
    asm volatile("s_waitcnt lgkmcnt(0)" ::: "memory");                         \
    __builtin_amdgcn_sched_barrier(0);                                         \
    __builtin_amdgcn_s_barrier(); /* gy prefetch stays in flight */            \
    __builtin_amdgcn_sched_barrier(0);                                         \
  }

    for (int t = 0; t < NT; t += 2) {
      YSTEP(t, gA0, gA1, gA2, gA3);
      YSTEP(t + 1, gB0, gB1, gB2, gB3);
    }
#undef YSTEP
    {  // epilogue: FC of h1[NT-1] -> out[NT-1]
      half8 b0_ = *(const half8*)&hfr[(NT + 1) & 1][0][l][0];
      half8 b1_ = *(const half8*)&hfr[(NT + 1) & 1][1][l][0];
      half8 b2_ = *(const half8*)&hfr[(NT + 1) & 1][2][l][0];
      half8 b3_ = *(const half8*)&hfr[(NT + 1) & 1][3][l][0];
      if (w < 4) {
        half8 f0 = *(const half8*)&fcl[w][0][l][0];
        half8 f1 = *(const half8*)&fcl[w][1][l][0];
        half8 f2 = *(const half8*)&fcl[w][2][l][0];
        half8 f3 = *(const half8*)&fcl[w][3][l][0];
        f32x4 afc = fcbv;
        afc = MFMA(f0, b0_, afc); afc = MFMA(f1, b1_, afc);
        afc = MFMA(f2, b2_, afc); afc = MFMA(f3, b3_, afc);
        *(f32x4*)(outG + (size_t)(NT - 1) * 64) = afc;
      }
    }
  }
}

extern "C" void kernel_launch(void* const* d_in, const int* in_sizes, int n_in,
                              void* d_out, int out_size, void* d_ws, size_t ws_size,
                              hipStream_t stream) {
  const float* x     = (const float*)d_in[0];
  const float* w_ih0 = (const float*)d_in[1];
  const float* w_hh0 = (const float*)d_in[2];
  const float* w_ih1 = (const float*)d_in[3];
  const float* w_hh1 = (const float*)d_in[4];
  const float* b_ih  = (const float*)d_in[5];
  const float* b_hh  = (const float*)d_in[6];
  const float* fc_w  = (const float*)d_in[7];
  const float* fc_b  = (const float*)d_in[8];

  // ws layout: h0 ring 8 MB | gx ring 16 MB | gy ring 16 MB | flags 4 KB
  _Float16* ringH0 = (_Float16*)d_ws;
  float* ringGX = (float*)((char*)d_ws + (8u << 20));
  float* ringGY = (float*)((char*)d_ws + (24u << 20));
  unsigned* flags = (unsigned*)((char*)d_ws + (40u << 20));

  hipMemsetAsync(flags, 0, 4096, stream);
  lstm_main<<<32, 512, 0, stream>>>(x, w_ih0, w_hh0, w_ih1, w_hh1, b_ih, b_hh,
                                    fc_w, fc_b, ringH0, ringGX, ringGY, flags,
                                    (float*)d_out);
}